// Round 3
// baseline (398.193 us; speedup 1.0000x reference)
//
#include <hip/hip_runtime.h>
#include <math.h>

#define BATCH 32
#define CH    256
#define HH    56
#define WW    56
#define HW    3136
#define KS    7
#define KK    49
#define PSTR  52            // padded per-image stride of p (floats), 16B multiple
#define NIMG  8192          // BATCH*CH

// conv geometry: padded image in LDS, pitch 68 floats (68 mod 32 = 4 -> bank twist)
#define CPITCH 68           // 4 zero | 56 image | 4 zero | 4 unused
#define CROWS  62           // 3 | 56 | 3
#define IMGF   (CROWS*CPITCH)   // 4216 floats = 16864 B

// ---- Kernel 1: pool + per-image partial BN stats ----
// block = one image (b,c). 784 float4 reads; each f4 sums into its pooling cell
// via LDS atomicAdd (f4 never spans a cell: 8-col blocks, 4-aligned).
__global__ __launch_bounds__(256) void pool_kernel(const float* __restrict__ x,
                                                   float* __restrict__ p,
                                                   float* __restrict__ s1,
                                                   float* __restrict__ s2) {
    __shared__ float cell[KK];
    const int img = blockIdx.x;
    const int t = threadIdx.x;
    if (t < KK) cell[t] = 0.f;
    __syncthreads();
    const float4* xi = (const float4*)(x + (size_t)img * HW);
    #pragma unroll
    for (int k = 0; k < 4; ++k) {
        const int i = k * 256 + t;
        if (i < 784) {
            const float4 v = xi[i];
            const int row = i / 14, q = i - row * 14;
            atomicAdd(&cell[(row >> 3) * KS + (q >> 1)], v.x + v.y + v.z + v.w);
        }
    }
    __syncthreads();
    if (t < 64) {
        const float v = (t < KK) ? cell[t] * (1.0f / 64.0f) : 0.f;
        if (t < KK) p[(size_t)img * PSTR + t] = v;
        float a = v, b2 = v * v;
        #pragma unroll
        for (int o = 32; o >= 1; o >>= 1) {
            a  += __shfl_down(a, o, 64);
            b2 += __shfl_down(b2, o, 64);
        }
        if (t == 0) { s1[img] = a; s2[img] = b2; }
    }
}

// ---- Kernel 2: BN finalize + Linear(49->7) + LayerNorm(C,7) + sigmoid + Linear(7->49) ----
// block = batch sample b; thread = channel c. BN stats finalized per-thread from s1/s2.
__global__ __launch_bounds__(256) void mid_kernel(const float* __restrict__ p,
                                                  const float* __restrict__ s1,
                                                  const float* __restrict__ s2,
                                                  const float* __restrict__ bng,
                                                  const float* __restrict__ bnb,
                                                  const float* __restrict__ w0,
                                                  const float* __restrict__ lng,
                                                  const float* __restrict__ lnb,
                                                  const float* __restrict__ w1,
                                                  float* __restrict__ ker) {
    const int b = blockIdx.x, c = threadIdx.x;
    __shared__ float s_w0[KS * KK], s_w1[KK * KS];
    __shared__ float r1[4], r2[4];
    for (int i = c; i < KS * KK; i += 256) { s_w0[i] = w0[i]; s_w1[i] = w1[i]; }

    // BN stats for channel c (coalesced: lane c reads stride-1 across c)
    float S = 0.f, S2 = 0.f;
    #pragma unroll
    for (int bb = 0; bb < BATCH; ++bb) { S += s1[bb * CH + c]; S2 += s2[bb * CH + c]; }
    const float binv = 1.0f / (float)(BATCH * KK);
    const float mu   = S * binv;
    const float bvar = S2 * binv - mu * mu;          // biased, matches ref
    const float brs  = rsqrtf(bvar + 1e-5f);
    const float sc = bng[c] * brs;
    const float sh = bnb[c] - mu * sc;

    __syncthreads();                                  // s_w0/s_w1 ready

    float tmp[PSTR];
    const float4* pp4 = (const float4*)(p + ((size_t)(b * CH) + c) * PSTR);
    #pragma unroll
    for (int q = 0; q < PSTR / 4; ++q) ((float4*)tmp)[q] = pp4[q];
    float pn[KK];
    #pragma unroll
    for (int i = 0; i < KK; ++i) pn[i] = tmp[i] * sc + sh;

    float v[KS];
    float ls = 0.f, ls2 = 0.f;
    #pragma unroll
    for (int j = 0; j < KS; ++j) {
        float a = 0.f;
        #pragma unroll
        for (int i = 0; i < KK; ++i) a += pn[i] * s_w0[j * KK + i];   // v = pn @ w0^T
        v[j] = a; ls += a; ls2 += a * a;
    }
    #pragma unroll
    for (int o = 32; o >= 1; o >>= 1) {
        ls  += __shfl_down(ls, o, 64);
        ls2 += __shfl_down(ls2, o, 64);
    }
    const int w = c >> 6;
    if ((c & 63) == 0) { r1[w] = ls; r2[w] = ls2; }
    __syncthreads();
    const float Sl  = r1[0] + r1[1] + r1[2] + r1[3];
    const float Sl2 = r2[0] + r2[1] + r2[2] + r2[3];
    const float inv = 1.0f / (float)(CH * KS);
    const float m   = Sl * inv;
    const float var = Sl2 * inv - m * m;              // biased, matches ref
    const float rs  = rsqrtf(var + 1e-5f);
    float sg[KS];
    #pragma unroll
    for (int j = 0; j < KS; ++j) {
        const float vn = (v[j] - m) * rs * lng[c * KS + j] + lnb[c * KS + j];
        sg[j] = 1.0f / (1.0f + expf(-vn));
    }
    float* ko = ker + ((size_t)(b * CH) + c) * KK;
    #pragma unroll
    for (int i = 0; i < KK; ++i) {
        float a = 0.f;
        #pragma unroll
        for (int j = 0; j < KS; ++j) a += sg[j] * s_w1[i * KS + j];   // @ w1^T
        ko[i] = a;
    }
}

// ---- Kernel 3: depthwise 7x7 'SAME' conv ----
// block = 1 image, 112 threads. thread ti: g = ti%14 (4-col group, g-fastest so
// consecutive lanes hit consecutive bank-quads), s = ti/14 (7-row strip).
// pitch 68: bank-quad = (7s + j + g) mod 8 -> <=2-way conflict per 8-lane phase.
__global__ __launch_bounds__(112, 4) void conv_kernel(const float* __restrict__ x,
                                                      const float* __restrict__ ker,
                                                      float* __restrict__ out) {
    __shared__ __align__(16) float pad[IMGF];
    __shared__ __align__(16) float kf[KK];
    const int img = blockIdx.x;
    const int t = threadIdx.x;
    const float* xi = x + (size_t)img * HW;

    // zero only the read borders: rows 0-2,59-61 full (6x17 f4) + side f4s rows 3..58
    const float4 z = make_float4(0.f, 0.f, 0.f, 0.f);
    for (int i = t; i < 214; i += 112) {
        int row, cq;
        if (i < 102) { const int r2 = i / 17; row = (r2 < 3) ? r2 : 56 + r2; cq = i % 17; }
        else         { const int j = i - 102; row = (j >> 1) + 3; cq = (j & 1) ? 15 : 0; }
        *(float4*)(pad + row * CPITCH + cq * 4) = z;
    }
    if (t < KK) kf[t] = ker[(size_t)img * KK + t];
    __syncthreads();

    // stage interior: 56 rows x 14 f4 = 784 tasks, 7 per thread (coalesced)
    #pragma unroll
    for (int k = 0; k < 7; ++k) {
        const int task = k * 112 + t;
        const int row = task / 14, q = task - row * 14;
        const float4 v = *(const float4*)(xi + row * WW + q * 4);
        *(float4*)(pad + (row + 3) * CPITCH + 4 + q * 4) = v;
    }
    __syncthreads();

    const int g = t % 14;          // col group: output cols 4g..4g+3
    const int s = t / 14;          // row strip: output rows 7s..7s+6
    const float* P = pad + (7 * s) * CPITCH + 4 * g;

    float kv[KK];
    #pragma unroll
    for (int i = 0; i < KK; ++i) kv[i] = kf[i];   // broadcast, free

    float acc[KS][4];
    #pragma unroll
    for (int r = 0; r < KS; ++r)
        #pragma unroll
        for (int c = 0; c < 4; ++c) acc[r][c] = 0.f;

    #pragma unroll
    for (int j = 0; j < 13; ++j) {
        const float4 A  = *(const float4*)(P + j * CPITCH);
        const float4 Bv = *(const float4*)(P + j * CPITCH + 4);
        const float4 Cv = *(const float4*)(P + j * CPITCH + 8);
        const float w[12] = {A.x, A.y, A.z, A.w, Bv.x, Bv.y, Bv.z, Bv.w,
                             Cv.x, Cv.y, Cv.z, Cv.w};
        #pragma unroll
        for (int kr = 0; kr < KS; ++kr) {
            const int rr = j - kr;
            if (rr < 0 || rr > 6) continue;           // compile-time after unroll
            #pragma unroll
            for (int kw = 0; kw < KS; ++kw) {
                const float kvv = kv[kr * KS + kw];
                #pragma unroll
                for (int c = 0; c < 4; ++c)
                    acc[rr][c] += w[kw + 1 + c] * kvv;
            }
        }
    }

    float* O = out + (size_t)img * HW + (7 * s) * WW + 4 * g;
    #pragma unroll
    for (int rr = 0; rr < KS; ++rr)
        *(float4*)(O + rr * WW) = make_float4(acc[rr][0], acc[rr][1], acc[rr][2], acc[rr][3]);
}

extern "C" void kernel_launch(void* const* d_in, const int* in_sizes, int n_in,
                              void* d_out, int out_size, void* d_ws, size_t ws_size,
                              hipStream_t stream) {
    const float* x   = (const float*)d_in[0];
    const float* bng = (const float*)d_in[1];
    const float* bnb = (const float*)d_in[2];
    const float* w0  = (const float*)d_in[3];
    const float* lng = (const float*)d_in[4];
    const float* lnb = (const float*)d_in[5];
    const float* w1  = (const float*)d_in[6];
    float* out = (float*)d_out;

    float* ws   = (float*)d_ws;
    float* p    = ws;                        // NIMG*PSTR
    float* s1   = p + (size_t)NIMG * PSTR;   // NIMG
    float* s2   = s1 + NIMG;                 // NIMG
    float* kern = s2 + NIMG;                 // NIMG*KK

    hipLaunchKernelGGL(pool_kernel, dim3(NIMG),  dim3(256), 0, stream, x, p, s1, s2);
    hipLaunchKernelGGL(mid_kernel,  dim3(BATCH), dim3(256), 0, stream, p, s1, s2,
                       bng, bnb, w0, lng, lnb, w1, kern);
    hipLaunchKernelGGL(conv_kernel, dim3(NIMG),  dim3(112), 0, stream, x, kern, out);
}